// Round 7
// baseline (505.799 us; speedup 1.0000x reference)
//
#include <hip/hip_runtime.h>

typedef unsigned short ushort_t;
typedef unsigned int uint32;
typedef __attribute__((ext_vector_type(8))) short short8;
typedef __attribute__((ext_vector_type(4))) float f32x4;

#define LOG2E   1.4426950408889634f
#define LOG2E2  2.8853900817779268f
#define MFMA16  __builtin_amdgcn_mfma_f32_16x16x32_bf16

static __device__ __forceinline__ ushort_t f2bf(float f) {
    uint32 u = __float_as_uint(f);
    u += 0x7FFFu + ((u >> 16) & 1u);
    return (ushort_t)(u >> 16);
}
static __device__ __forceinline__ float rcp_(float x) { return __builtin_amdgcn_rcpf(x); }
static __device__ __forceinline__ float ex2_(float x) { return __builtin_amdgcn_exp2f(x); }
// sigmoid with pre-scaled arg (x already multiplied by log2e)
static __device__ __forceinline__ float sigp_(float x) { return rcp_(1.0f + ex2_(-x)); }

// gates (i,f,g,o pre-scaled by log2e / 2log2e) -> new cell + h
static __device__ __forceinline__ float gate_update(const f32x4 a, float& cc) {
    float i_ = sigp_(a[0]);
    float f_ = sigp_(a[1]);
    float g_ = fmaf(2.f, sigp_(a[2]), -1.f);
    float o_ = sigp_(a[3]);
    cc = fmaf(f_, cc, i_ * g_);
    return o_ * fmaf(2.f, sigp_(cc * LOG2E2), -1.f);
}

// ---------------- one LSTM layer, persistent, 8 waves x 4 tiles ----------------
// 64 blocks x 512 threads; block owns 16 batch rows. Wave w owns gate rows
// [w*64, w*64+64) = 4 M-tiles; thread (w,kg,n) outputs 4 contiguous h-cols
// f0..f0+3, f0 = w*16+kg*4. Weights packed inline from f32 (A-frag layout:
// lane holds A[m=lane&15][k=(lane>>4)*8+e]; tile row m=kga*4+j -> weight row
// j*128 + w*16 + kga*4 + tq, pre-scaled by log2e (2log2e for g)).
// LDS k-major: feature f of batch n at ushort [f>>5][(f>>3)&3][n][f&7].
// L0 stores per-step k-major 4KB records one step LATE (drain off critical path);
// L1 phase (same block) reads them back with workgroup-scope (L1-bypass) loads.
template<int KT, bool IS_L0>
__device__ __forceinline__ void run_phase(
    const float* __restrict__ xin_f32,     // IS_L0: [B,T,64] f32
    const uint32* __restrict__ xin_rec,    // !IS_L0: k-major records
    const float* __restrict__ Whh, const float* __restrict__ Wih,
    const float* __restrict__ bih, const float* __restrict__ bhh,
    uint32* __restrict__ hrec,             // IS_L0 out
    float* __restrict__ lastH,             // !IS_L0 out
    ushort_t* hb, ushort_t* xb)
{
    constexpr int KX  = KT - 4;
    constexpr int DIN = IS_L0 ? 64 : 128;
    const int tid  = threadIdx.x;
    const int w    = tid >> 6;
    const int lane = tid & 63;
    const int n    = lane & 15;
    const int kg   = lane >> 4;
    const int b0   = blockIdx.x * 16;

    // ---- inline weight pack -> registers (held for whole phase) ----
    const int j   = lane & 3;
    const int kga = (lane >> 2) & 3;
    short8 wf[4][KT];
#pragma unroll
    for (int tq = 0; tq < 4; ++tq) {
        const int arow = j * 128 + w * 16 + kga * 4 + tq;
        const float scale = (j == 2) ? LOG2E2 : LOG2E;
#pragma unroll
        for (int kt = 0; kt < KT; ++kt) {
            const int k0 = kt * 32 + kg * 8;
            const float* src = (k0 < 128) ? (Whh + (long)arow * 128 + k0)
                                          : (Wih + (long)arow * DIN + (k0 - 128));
            f32x4 v0 = *(const f32x4*)src;
            f32x4 v1 = *(const f32x4*)(src + 4);
            short8 s;
            s[0] = (short)f2bf(v0[0] * scale); s[1] = (short)f2bf(v0[1] * scale);
            s[2] = (short)f2bf(v0[2] * scale); s[3] = (short)f2bf(v0[3] * scale);
            s[4] = (short)f2bf(v1[0] * scale); s[5] = (short)f2bf(v1[1] * scale);
            s[6] = (short)f2bf(v1[2] * scale); s[7] = (short)f2bf(v1[3] * scale);
            wf[tq][kt] = s;
        }
    }
    f32x4 bias[4];
#pragma unroll
    for (int tq = 0; tq < 4; ++tq)
#pragma unroll
        for (int r = 0; r < 4; ++r) {
            int row = r * 128 + w * 16 + kg * 4 + tq;
            bias[tq][r] = (bih[row] + bhh[row]) * ((r == 2) ? LOG2E2 : LOG2E);
        }

    float cc0 = 0.f, cc1 = 0.f, cc2 = 0.f, cc3 = 0.f;
    const int f0   = w * 16 + kg * 4;
    const int idxA = ((f0 >> 5) * 4 + ((f0 >> 3) & 3)) * 64 + n * 4 + ((f0 & 7) >> 1);

    // staging maps
    const int se  = (tid & 3) * 2;
    const int sn  = (tid >> 2) & 15;
    const int skg = (tid >> 6) & 3;
    const int skx = tid >> 8;
    const long xbase = (long)(b0 + sn) * (256 * 64) + (skx * 32 + skg * 8 + se);
    const int  sidx  = (skx * 4 + skg) * 64 + sn * 4 + (se >> 1);
    const long rb    = (long)blockIdx.x * (256 * 1024);     // u32 units

    // init LDS: zero h state (buf 0), stage x[t=0]
    ((uint32*)hb)[tid] = 0u;
    ((uint32*)hb)[tid + 512] = 0u;
    if constexpr (IS_L0) {
        float2 xv = *(const float2*)&xin_f32[xbase];
        uint32 xp; asm("v_cvt_pk_bf16_f32 %0, %1, %2" : "=v"(xp) : "v"(xv.x), "v"(xv.y));
        ((uint32*)xb)[sidx] = xp;
    } else {
        ((uint32*)xb)[tid] = __hip_atomic_load(&xin_rec[rb + tid],
                                __ATOMIC_RELAXED, __HIP_MEMORY_SCOPE_WORKGROUP);
        ((uint32*)xb)[tid + 512] = __hip_atomic_load(&xin_rec[rb + tid + 512],
                                __ATOMIC_RELAXED, __HIP_MEMORY_SCOPE_WORKGROUP);
    }
    __syncthreads();

    uint2 prev_hpv = {0u, 0u};
#pragma unroll 1
    for (int t = 0; t < 256; ++t) {
        const int cur = t & 1, nxt = cur ^ 1;
        const ushort_t* hbc = hb + cur * 2048;
        const ushort_t* xbc = xb + cur * (KX * 512);
        const bool pf = (t + 1 < 256);
        float2 xf = {0.f, 0.f}; uint32 xu0 = 0, xu1 = 0;
        if (pf) {
            if constexpr (IS_L0) {
                xf = *(const float2*)&xin_f32[xbase + (t + 1) * 64];
            } else {
                xu0 = __hip_atomic_load(&xin_rec[rb + (t + 1) * 1024 + tid],
                        __ATOMIC_RELAXED, __HIP_MEMORY_SCOPE_WORKGROUP);
                xu1 = __hip_atomic_load(&xin_rec[rb + (t + 1) * 1024 + tid + 512],
                        __ATOMIC_RELAXED, __HIP_MEMORY_SCOPE_WORKGROUP);
            }
        }
        // store PREVIOUS step's record: full step to retire before next drain
        if constexpr (IS_L0) {
            if (t > 0) *(uint2*)&hrec[rb + (long)(t - 1) * 1024 + idxA] = prev_hpv;
        }

        // B-fragments (shared across the 4 tiles)
        short8 hfr0 = *(const short8*)&hbc[0 * 512 + kg * 128 + n * 8];
        short8 hfr1 = *(const short8*)&hbc[1 * 512 + kg * 128 + n * 8];
        short8 hfr2 = *(const short8*)&hbc[2 * 512 + kg * 128 + n * 8];
        short8 hfr3 = *(const short8*)&hbc[3 * 512 + kg * 128 + n * 8];
        short8 xfr[KX];
#pragma unroll
        for (int kx = 0; kx < KX; ++kx)
            xfr[kx] = *(const short8*)&xbc[kx * 512 + kg * 128 + n * 8];

        // MFMA chains, tiles 0..3 (bias as C-in)
        f32x4 a0 = MFMA16(wf[0][0], hfr0, bias[0], 0, 0, 0);
        f32x4 a1 = MFMA16(wf[1][0], hfr0, bias[1], 0, 0, 0);
        a0 = MFMA16(wf[0][1], hfr1, a0, 0, 0, 0);
        a1 = MFMA16(wf[1][1], hfr1, a1, 0, 0, 0);
        a0 = MFMA16(wf[0][2], hfr2, a0, 0, 0, 0);
        a1 = MFMA16(wf[1][2], hfr2, a1, 0, 0, 0);
        a0 = MFMA16(wf[0][3], hfr3, a0, 0, 0, 0);
        a1 = MFMA16(wf[1][3], hfr3, a1, 0, 0, 0);
#pragma unroll
        for (int kx = 0; kx < KX; ++kx) {
            a0 = MFMA16(wf[0][4 + kx], xfr[kx], a0, 0, 0, 0);
            a1 = MFMA16(wf[1][4 + kx], xfr[kx], a1, 0, 0, 0);
        }
        f32x4 a2 = MFMA16(wf[2][0], hfr0, bias[2], 0, 0, 0);
        f32x4 a3 = MFMA16(wf[3][0], hfr0, bias[3], 0, 0, 0);
        a2 = MFMA16(wf[2][1], hfr1, a2, 0, 0, 0);
        a3 = MFMA16(wf[3][1], hfr1, a3, 0, 0, 0);
        a2 = MFMA16(wf[2][2], hfr2, a2, 0, 0, 0);
        a3 = MFMA16(wf[3][2], hfr2, a3, 0, 0, 0);
        a2 = MFMA16(wf[2][3], hfr3, a2, 0, 0, 0);
        a3 = MFMA16(wf[3][3], hfr3, a3, 0, 0, 0);
#pragma unroll
        for (int kx = 0; kx < KX; ++kx) {
            a2 = MFMA16(wf[2][4 + kx], xfr[kx], a2, 0, 0, 0);
            a3 = MFMA16(wf[3][4 + kx], xfr[kx], a3, 0, 0, 0);
        }

        // elementwise tiles 0,1 — schedulable under tiles 2,3's MFMA chains
        float hv0 = gate_update(a0, cc0);
        float hv1 = gate_update(a1, cc1);

        // pin the MFMA/VALU interleave (tiles-2,3 MFMAs between elem VALU bursts)
#pragma unroll
        for (int r_ = 0; r_ < (KT == 6 ? 6 : 8); ++r_) {
            __builtin_amdgcn_sched_group_barrier(0x008, 2, 0);                 // 2 MFMA
            __builtin_amdgcn_sched_group_barrier(0x002, KT == 6 ? 8 : 6, 0);   // VALU
        }

        float hv2 = gate_update(a2, cc2);
        float hv3 = gate_update(a3, cc3);

        uint32 hp0, hp1;
        asm("v_cvt_pk_bf16_f32 %0, %1, %2" : "=v"(hp0) : "v"(hv0), "v"(hv1));
        asm("v_cvt_pk_bf16_f32 %0, %1, %2" : "=v"(hp1) : "v"(hv2), "v"(hv3));
        prev_hpv.x = hp0; prev_hpv.y = hp1;
        *(uint2*)&((uint32*)hb)[nxt * 1024 + idxA] = prev_hpv;

        if constexpr (!IS_L0) {
            if (t == 255) {
                f32x4 hv = {hv0, hv1, hv2, hv3};
                *(f32x4*)&lastH[(long)(b0 + n) * 128 + f0] = hv;
            }
        }
        if (pf) {
            if constexpr (IS_L0) {
                uint32 xp; asm("v_cvt_pk_bf16_f32 %0, %1, %2" : "=v"(xp) : "v"(xf.x), "v"(xf.y));
                ((uint32*)xb)[nxt * (KX * 256) + sidx] = xp;
            } else {
                ((uint32*)xb)[nxt * (KX * 256) + tid] = xu0;
                ((uint32*)xb)[nxt * (KX * 256) + tid + 512] = xu1;
            }
        }
        __syncthreads();
    }
    if constexpr (IS_L0)
        *(uint2*)&hrec[rb + 255L * 1024 + idxA] = prev_hpv;
}

__global__ __launch_bounds__(512)
void lstm_both(const float* __restrict__ x,
               const float* __restrict__ Whh0, const float* __restrict__ Wih0,
               const float* __restrict__ bih0, const float* __restrict__ bhh0,
               const float* __restrict__ Whh1, const float* __restrict__ Wih1,
               const float* __restrict__ bih1, const float* __restrict__ bhh1,
               uint32* __restrict__ h1k, float* __restrict__ lastH)
{
    __shared__ ushort_t hb[4096];   // 8 KiB: h double buffer
    __shared__ ushort_t xb[4096];   // 8 KiB: x double buffer (L0 uses half)
    run_phase<6, true >(x, nullptr, Whh0, Wih0, bih0, bhh0, h1k, nullptr, hb, xb);
    __syncthreads();
    run_phase<8, false>(nullptr, h1k, Whh1, Wih1, bih1, bhh1, nullptr, lastH, hb, xb);
}

// ---------------- head: LayerNorm + fc1(relu) + fc2 ----------------
__global__ __launch_bounds__(256)
void head_kernel(const float* __restrict__ lastH,
                 const float* __restrict__ ln_g, const float* __restrict__ ln_b,
                 const float* __restrict__ fc1w, const float* __restrict__ fc1b,
                 const float* __restrict__ fc2w, const float* __restrict__ fc2b,
                 float* __restrict__ out) {
    __shared__ float ylds[4][128];
    int w = threadIdx.x >> 6, lane = threadIdx.x & 63;
    int row = blockIdx.x * 4 + w;
    float x0 = lastH[row * 128 + lane];
    float x1 = lastH[row * 128 + 64 + lane];
    float s = x0 + x1;
    for (int off = 32; off; off >>= 1) s += __shfl_xor(s, off);
    float mu = s * (1.f / 128.f);
    float d0 = x0 - mu, d1 = x1 - mu;
    float v = d0 * d0 + d1 * d1;
    for (int off = 32; off; off >>= 1) v += __shfl_xor(v, off);
    float rs = rsqrtf(v * (1.f / 128.f) + 1e-5f);
    ylds[w][lane]      = d0 * rs * ln_g[lane]      + ln_b[lane];
    ylds[w][lane + 64] = d1 * rs * ln_g[lane + 64] + ln_b[lane + 64];
    __syncthreads();
    float a = fc1b[lane];
#pragma unroll 4
    for (int k = 0; k < 128; ++k) a += ylds[w][k] * fc1w[lane * 128 + k];
    float r = fmaxf(a, 0.f) * fc2w[lane];
    for (int off = 32; off; off >>= 1) r += __shfl_xor(r, off);
    if (lane == 0) out[row] = r + fc2b[0];
}

extern "C" void kernel_launch(void* const* d_in, const int* in_sizes, int n_in,
                              void* d_out, int out_size, void* d_ws, size_t ws_size,
                              hipStream_t stream) {
    const float* x    = (const float*)d_in[0];
    const float* Wih0 = (const float*)d_in[1];
    const float* Whh0 = (const float*)d_in[2];
    const float* bih0 = (const float*)d_in[3];
    const float* bhh0 = (const float*)d_in[4];
    const float* Wih1 = (const float*)d_in[5];
    const float* Whh1 = (const float*)d_in[6];
    const float* bih1 = (const float*)d_in[7];
    const float* bhh1 = (const float*)d_in[8];
    const float* ln_g = (const float*)d_in[9];
    const float* ln_b = (const float*)d_in[10];
    const float* fc1w = (const float*)d_in[11];
    const float* fc1b = (const float*)d_in[12];
    const float* fc2w = (const float*)d_in[13];
    const float* fc2b = (const float*)d_in[14];

    char* ws = (char*)d_ws;
    uint32* h1k   = (uint32*)(ws);                 // 64 blk x 256 t x 4 KiB = 64 MiB
    float*  lastH = (float*) (ws + 67108864);      // 512 KiB

    lstm_both<<<64, 512, 0, stream>>>(x, Whh0, Wih0, bih0, bhh0,
                                      Whh1, Wih1, bih1, bhh1, h1k, lastH);

    head_kernel<<<256, 256, 0, stream>>>(lastH, ln_g, ln_b, fc1w, fc1b, fc2w, fc2b,
                                         (float*)d_out);
}

// Round 8
// 386.102 us; speedup vs baseline: 1.3100x; 1.3100x over previous
//
#include <hip/hip_runtime.h>

typedef unsigned short ushort_t;
typedef unsigned int uint32;
typedef __attribute__((ext_vector_type(8))) short short8;
typedef __attribute__((ext_vector_type(4))) float f32x4;

#define LOG2E   1.4426950408889634f
#define LOG2E2  2.8853900817779268f
#define MFMA16  __builtin_amdgcn_mfma_f32_16x16x32_bf16
#define CHUNK_B 4            // 16-step chunks
#define CHUNK_M 15

static __device__ __forceinline__ ushort_t f2bf(float f) {
    uint32 u = __float_as_uint(f);
    u += 0x7FFFu + ((u >> 16) & 1u);
    return (ushort_t)(u >> 16);
}
static __device__ __forceinline__ float rcp_(float x) { return __builtin_amdgcn_rcpf(x); }
static __device__ __forceinline__ float ex2_(float x) { return __builtin_amdgcn_exp2f(x); }
// sigmoid with pre-scaled arg (x already multiplied by log2e)
static __device__ __forceinline__ float sigp_(float x) { return rcp_(1.0f + ex2_(-x)); }

// gates (i,f,g,o pre-scaled by log2e / 2log2e) -> new cell + h
static __device__ __forceinline__ float gate_update(const f32x4 a, float& cc) {
    float i_ = sigp_(a[0]);
    float f_ = sigp_(a[1]);
    float g_ = fmaf(2.f, sigp_(a[2]), -1.f);
    float o_ = sigp_(a[3]);
    cc = fmaf(f_, cc, i_ * g_);
    return o_ * fmaf(2.f, sigp_(cc * LOG2E2), -1.f);
}

// ---------------- prep: pack W into MFMA A-fragments (8-wave / 4-tile geometry) ----
// Wave w in [0,8), tile tq in [0,4). Tile row m = kga*4 + j (j = gate i,f,g,o)
// -> weight row = j*128 + hc, hc = w*16 + kga*4 + tq. Pre-scaled log2e / 2log2e(g).
template<int LAYER>
__global__ void prep_frag(const float* __restrict__ Whh, const float* __restrict__ Wih,
                          ushort_t* __restrict__ wfrag) {
    constexpr int KT  = (LAYER == 0) ? 6 : 8;
    constexpr int DIN = (LAYER == 0) ? 64 : 128;
    int i = blockIdx.x * 256 + threadIdx.x;
    int e    = i & 7;
    int lane = (i >> 3) & 63;
    int r3   = i >> 9;
    int kt   = r3 % KT;
    int r4   = r3 / KT;
    int tq   = r4 & 3;
    int w    = r4 >> 2;
    if (w >= 8) return;
    int ml  = lane & 15;
    int kga = ml >> 2;
    int j   = ml & 3;
    int k   = kt * 32 + (lane >> 4) * 8 + e;
    int row = j * 128 + w * 16 + kga * 4 + tq;
    float scale = (j == 2) ? LOG2E2 : LOG2E;
    float v = (k < 128) ? Whh[row * 128 + k] : Wih[row * DIN + (k - 128)];
    wfrag[i] = f2bf(v * scale);
}

__global__ void prep_bias(const float* __restrict__ bih0, const float* __restrict__ bhh0,
                          const float* __restrict__ bih1, const float* __restrict__ bhh1,
                          float* __restrict__ bp0, float* __restrict__ bp1,
                          uint32* __restrict__ flags) {
    int i = blockIdx.x * 256 + threadIdx.x;   // 0..1023
    flags[i] = 0u;                            // reset pipeline flags (graph-replay safe)
    flags[i + 1024] = 0u;
    int p = i & 511;
    int w = p >> 6, tq = (p >> 4) & 3, kga = (p >> 2) & 3, j = p & 3;
    int row = j * 128 + w * 16 + kga * 4 + tq;
    float scale = (j == 2) ? LOG2E2 : LOG2E;
    if (i < 512) bp0[p] = (bih0[row] + bhh0[row]) * scale;
    else         bp1[p] = (bih1[row] + bhh1[row]) * scale;
}

// ---------------- pipelined 2-layer LSTM, one dispatch ----------------
// 128 blocks x 512 threads (8 waves, 2/EU -> 256-reg budget). Blocks 0..63 = L0
// (producer), 64..127 = L1 (consumer), paired on batch group. Producer publishes
// 16-step chunks of k-major h-records via agent-scope stores + release flag;
// consumer polls 16x total (latency hidden by 2-step prefetch slack).
// x-decoupling: xacc[t+1] (= bias + Wx*x[t+1]) is computed during step t with
// independent MFMAs that overlap the elementwise VALU phase; the critical chain
// per step is only the 4 h-k-step MFMAs (C-in = xacc).
template<int KT, bool IS_L0>
__device__ __forceinline__ void run_phase(
    const int blk,
    const float* __restrict__ xin_f32,     // IS_L0: [B,T,64] f32
    const uint32* __restrict__ xin_rec,    // !IS_L0: k-major records
    const ushort_t* __restrict__ wfrag,
    const float* __restrict__ biasp,
    uint32* __restrict__ hrec,             // IS_L0 out
    float* __restrict__ lastH,             // !IS_L0 out
    uint32* __restrict__ flagp,
    ushort_t* hb, ushort_t* xb)
{
    constexpr int KX = KT - 4;
    constexpr int XW = KX * 256;           // u32 per x slot
    const int tid  = threadIdx.x;
    const int w    = tid >> 6;
    const int lane = tid & 63;
    const int n    = lane & 15;
    const int kg   = lane >> 4;
    const int b0   = blk * 16;

    // weights -> registers (held entire phase), split h-part / x-part
    short8 wfh[4][4];
    short8 wfx[4][KX];
#pragma unroll
    for (int tq = 0; tq < 4; ++tq) {
#pragma unroll
        for (int kt = 0; kt < 4; ++kt)
            wfh[tq][kt] = *(const short8*)&wfrag[(((w * 4 + tq) * KT + kt) * 64 + lane) * 8];
#pragma unroll
        for (int kx = 0; kx < KX; ++kx)
            wfx[tq][kx] = *(const short8*)&wfrag[(((w * 4 + tq) * KT + 4 + kx) * 64 + lane) * 8];
    }
    f32x4 bias[4];
#pragma unroll
    for (int tq = 0; tq < 4; ++tq)
        bias[tq] = *(const f32x4*)&biasp[w * 64 + tq * 16 + kg * 4];

    float cc[4] = {0.f, 0.f, 0.f, 0.f};
    const int f0   = w * 16 + kg * 4;
    const int idxA = ((f0 >> 5) * 4 + ((f0 >> 3) & 3)) * 64 + n * 4 + ((f0 & 7) >> 1);
    const int foff = kg * 128 + n * 8;

    // staging maps
    const int se  = (tid & 3) * 2;
    const int sn  = (tid >> 2) & 15;
    const int skg = (tid >> 6) & 3;
    const int skx = tid >> 8;
    const long xbase = (long)(b0 + sn) * (256 * 64) + (skx * 32 + skg * 8 + se);
    const int  sidx  = (skx * 4 + skg) * 64 + sn * 4 + (se >> 1);
    const long rb    = (long)blk * (256 * 1024);     // u32 units

    uint32 lastF = 0;

    // prologue: zero h state (slot 0), stage x[0]->slot0, x[1]->slot1
    ((uint32*)hb)[tid] = 0u;
    ((uint32*)hb)[tid + 512] = 0u;
    if constexpr (IS_L0) {
        float2 x0 = *(const float2*)&xin_f32[xbase];
        float2 x1 = *(const float2*)&xin_f32[xbase + 64];
        uint32 p0, p1;
        asm("v_cvt_pk_bf16_f32 %0, %1, %2" : "=v"(p0) : "v"(x0.x), "v"(x0.y));
        asm("v_cvt_pk_bf16_f32 %0, %1, %2" : "=v"(p1) : "v"(x1.x), "v"(x1.y));
        ((uint32*)xb)[sidx] = p0;
        ((uint32*)xb)[XW + sidx] = p1;
    } else {
        lastF = __hip_atomic_load(flagp, __ATOMIC_ACQUIRE, __HIP_MEMORY_SCOPE_AGENT);
        while (lastF < 1u) {
            __builtin_amdgcn_s_sleep(8);
            lastF = __hip_atomic_load(flagp, __ATOMIC_ACQUIRE, __HIP_MEMORY_SCOPE_AGENT);
        }
        ((uint32*)xb)[tid]            = __hip_atomic_load(&xin_rec[rb + tid], __ATOMIC_RELAXED, __HIP_MEMORY_SCOPE_AGENT);
        ((uint32*)xb)[tid + 512]      = __hip_atomic_load(&xin_rec[rb + tid + 512], __ATOMIC_RELAXED, __HIP_MEMORY_SCOPE_AGENT);
        ((uint32*)xb)[XW + tid]       = __hip_atomic_load(&xin_rec[rb + 1024 + tid], __ATOMIC_RELAXED, __HIP_MEMORY_SCOPE_AGENT);
        ((uint32*)xb)[XW + tid + 512] = __hip_atomic_load(&xin_rec[rb + 1024 + tid + 512], __ATOMIC_RELAXED, __HIP_MEMORY_SCOPE_AGENT);
    }
    __syncthreads();

    // xacc for step 0 from x[0] (slot 0)
    f32x4 xacc[4];
    {
        short8 xf_[KX];
#pragma unroll
        for (int kx = 0; kx < KX; ++kx)
            xf_[kx] = *(const short8*)&xb[kx * 512 + foff];
#pragma unroll
        for (int tq = 0; tq < 4; ++tq) {
            xacc[tq] = MFMA16(wfx[tq][0], xf_[0], bias[tq], 0, 0, 0);
#pragma unroll
            for (int kx = 1; kx < KX; ++kx)
                xacc[tq] = MFMA16(wfx[tq][kx], xf_[kx], xacc[tq], 0, 0, 0);
        }
    }
    __syncthreads();   // protect slot 0 before step-0 overwrites it with x[2]

    uint2 prev = {0u, 0u};
#pragma unroll 1
    for (int t = 0; t < 255; ++t) {
        const int cs = t & 1;
        const bool pf2 = (t < 254);                  // x[t+2] exists
        float2 xf = {0.f, 0.f}; uint32 xu0 = 0, xu1 = 0;
        if (pf2) {
            if constexpr (IS_L0) {
                xf = *(const float2*)&xin_f32[xbase + (long)(t + 2) * 64];
            } else {
                if (((t + 2) & CHUNK_M) == 0) {
                    const uint32 want = ((uint32)(t + 2) >> CHUNK_B) + 1u;
                    if (lastF < want) {
                        lastF = __hip_atomic_load(flagp, __ATOMIC_ACQUIRE, __HIP_MEMORY_SCOPE_AGENT);
                        while (lastF < want) {
                            __builtin_amdgcn_s_sleep(8);
                            lastF = __hip_atomic_load(flagp, __ATOMIC_ACQUIRE, __HIP_MEMORY_SCOPE_AGENT);
                        }
                    }
                }
                xu0 = __hip_atomic_load(&xin_rec[rb + (long)(t + 2) * 1024 + tid], __ATOMIC_RELAXED, __HIP_MEMORY_SCOPE_AGENT);
                xu1 = __hip_atomic_load(&xin_rec[rb + (long)(t + 2) * 1024 + tid + 512], __ATOMIC_RELAXED, __HIP_MEMORY_SCOPE_AGENT);
            }
        }
        // store previous step's record (full step of slack before the next drain)
        if constexpr (IS_L0) {
            if (t > 0) {
                __hip_atomic_store(&hrec[rb + (long)(t - 1) * 1024 + idxA],     prev.x, __ATOMIC_RELAXED, __HIP_MEMORY_SCOPE_AGENT);
                __hip_atomic_store(&hrec[rb + (long)(t - 1) * 1024 + idxA + 1], prev.y, __ATOMIC_RELAXED, __HIP_MEMORY_SCOPE_AGENT);
            }
        }

        // fragments
        short8 hfr[4];
#pragma unroll
        for (int kt = 0; kt < 4; ++kt)
            hfr[kt] = *(const short8*)&hb[cs * 2048 + kt * 512 + foff];
        short8 xfr[KX];
#pragma unroll
        for (int kx = 0; kx < KX; ++kx)
            xfr[kx] = *(const short8*)&xb[(cs ^ 1) * (KX * 512) + kx * 512 + foff];

        // gates for step t: 4-deep h-chain, C-in = xacc (bias + x[t] part)
        f32x4 acc[4];
#pragma unroll
        for (int tq = 0; tq < 4; ++tq) {
            acc[tq] = MFMA16(wfh[tq][0], hfr[0], xacc[tq], 0, 0, 0);
#pragma unroll
            for (int kt = 1; kt < 4; ++kt)
                acc[tq] = MFMA16(wfh[tq][kt], hfr[kt], acc[tq], 0, 0, 0);
        }
        // xacc for step t+1 — independent MFMAs, overlap the elementwise below
#pragma unroll
        for (int tq = 0; tq < 4; ++tq) {
            xacc[tq] = MFMA16(wfx[tq][0], xfr[0], bias[tq], 0, 0, 0);
#pragma unroll
            for (int kx = 1; kx < KX; ++kx)
                xacc[tq] = MFMA16(wfx[tq][kx], xfr[kx], xacc[tq], 0, 0, 0);
        }

        float hv0 = gate_update(acc[0], cc[0]);
        float hv1 = gate_update(acc[1], cc[1]);
        float hv2 = gate_update(acc[2], cc[2]);
        float hv3 = gate_update(acc[3], cc[3]);

        uint32 hp0, hp1;
        asm("v_cvt_pk_bf16_f32 %0, %1, %2" : "=v"(hp0) : "v"(hv0), "v"(hv1));
        asm("v_cvt_pk_bf16_f32 %0, %1, %2" : "=v"(hp1) : "v"(hv2), "v"(hv3));
        prev.x = hp0; prev.y = hp1;
        *(uint2*)&((uint32*)hb)[(cs ^ 1) * 1024 + idxA] = prev;

        if (pf2) {
            if constexpr (IS_L0) {
                uint32 xp;
                asm("v_cvt_pk_bf16_f32 %0, %1, %2" : "=v"(xp) : "v"(xf.x), "v"(xf.y));
                ((uint32*)xb)[cs * XW + sidx] = xp;
            } else {
                ((uint32*)xb)[cs * XW + tid] = xu0;
                ((uint32*)xb)[cs * XW + tid + 512] = xu1;
            }
        }
        __syncthreads();
        if constexpr (IS_L0) {
            if (tid == 0 && t > 0 && (t & CHUNK_M) == 0)
                __hip_atomic_store(flagp, (uint32)(t >> CHUNK_B), __ATOMIC_RELEASE, __HIP_MEMORY_SCOPE_AGENT);
        }
    }

    // t = 255 (peeled): gates only; h state in slot 1
    {
        short8 hfr[4];
#pragma unroll
        for (int kt = 0; kt < 4; ++kt)
            hfr[kt] = *(const short8*)&hb[2048 + kt * 512 + foff];
        f32x4 acc[4];
#pragma unroll
        for (int tq = 0; tq < 4; ++tq) {
            acc[tq] = MFMA16(wfh[tq][0], hfr[0], xacc[tq], 0, 0, 0);
#pragma unroll
            for (int kt = 1; kt < 4; ++kt)
                acc[tq] = MFMA16(wfh[tq][kt], hfr[kt], acc[tq], 0, 0, 0);
        }
        float hv0 = gate_update(acc[0], cc[0]);
        float hv1 = gate_update(acc[1], cc[1]);
        float hv2 = gate_update(acc[2], cc[2]);
        float hv3 = gate_update(acc[3], cc[3]);
        if constexpr (IS_L0) {
            uint32 hp0, hp1;
            asm("v_cvt_pk_bf16_f32 %0, %1, %2" : "=v"(hp0) : "v"(hv0), "v"(hv1));
            asm("v_cvt_pk_bf16_f32 %0, %1, %2" : "=v"(hp1) : "v"(hv2), "v"(hv3));
            __hip_atomic_store(&hrec[rb + 254L * 1024 + idxA],     prev.x, __ATOMIC_RELAXED, __HIP_MEMORY_SCOPE_AGENT);
            __hip_atomic_store(&hrec[rb + 254L * 1024 + idxA + 1], prev.y, __ATOMIC_RELAXED, __HIP_MEMORY_SCOPE_AGENT);
            __hip_atomic_store(&hrec[rb + 255L * 1024 + idxA],     hp0,    __ATOMIC_RELAXED, __HIP_MEMORY_SCOPE_AGENT);
            __hip_atomic_store(&hrec[rb + 255L * 1024 + idxA + 1], hp1,    __ATOMIC_RELAXED, __HIP_MEMORY_SCOPE_AGENT);
            __syncthreads();   // drains all waves' stores (vmcnt(0) before barrier)
            if (tid == 0)
                __hip_atomic_store(flagp, 16u, __ATOMIC_RELEASE, __HIP_MEMORY_SCOPE_AGENT);
        } else {
            f32x4 hv = {hv0, hv1, hv2, hv3};
            *(f32x4*)&lastH[(long)(b0 + n) * 128 + f0] = hv;
        }
    }
}

__global__ __launch_bounds__(512, 2)
void lstm_pipe(const float* __restrict__ x,
               const ushort_t* __restrict__ wf0, const ushort_t* __restrict__ wf1,
               const float* __restrict__ bp0, const float* __restrict__ bp1,
               uint32* __restrict__ h1k, float* __restrict__ lastH,
               uint32* __restrict__ flags)
{
    __shared__ ushort_t hb[4096];   // 8 KiB: h double buffer
    __shared__ ushort_t xb[4096];   // 8 KiB: x double buffer (L0 uses half)
    const int blk = blockIdx.x;
    if (blk < 64)
        run_phase<6, true >(blk, x, nullptr, wf0, bp0, h1k, nullptr,
                            &flags[blk * 32], hb, xb);
    else
        run_phase<8, false>(blk - 64, nullptr, h1k, wf1, bp1, nullptr, lastH,
                            &flags[(blk - 64) * 32], hb, xb);
}

// ---------------- head: LayerNorm + fc1(relu) + fc2 ----------------
__global__ __launch_bounds__(256)
void head_kernel(const float* __restrict__ lastH,
                 const float* __restrict__ ln_g, const float* __restrict__ ln_b,
                 const float* __restrict__ fc1w, const float* __restrict__ fc1b,
                 const float* __restrict__ fc2w, const float* __restrict__ fc2b,
                 float* __restrict__ out) {
    __shared__ float ylds[4][128];
    int w = threadIdx.x >> 6, lane = threadIdx.x & 63;
    int row = blockIdx.x * 4 + w;
    float x0 = lastH[row * 128 + lane];
    float x1 = lastH[row * 128 + 64 + lane];
    float s = x0 + x1;
    for (int off = 32; off; off >>= 1) s += __shfl_xor(s, off);
    float mu = s * (1.f / 128.f);
    float d0 = x0 - mu, d1 = x1 - mu;
    float v = d0 * d0 + d1 * d1;
    for (int off = 32; off; off >>= 1) v += __shfl_xor(v, off);
    float rs = rsqrtf(v * (1.f / 128.f) + 1e-5f);
    ylds[w][lane]      = d0 * rs * ln_g[lane]      + ln_b[lane];
    ylds[w][lane + 64] = d1 * rs * ln_g[lane + 64] + ln_b[lane + 64];
    __syncthreads();
    float a = fc1b[lane];
#pragma unroll 4
    for (int k = 0; k < 128; ++k) a += ylds[w][k] * fc1w[lane * 128 + k];
    float r = fmaxf(a, 0.f) * fc2w[lane];
    for (int off = 32; off; off >>= 1) r += __shfl_xor(r, off);
    if (lane == 0) out[row] = r + fc2b[0];
}

extern "C" void kernel_launch(void* const* d_in, const int* in_sizes, int n_in,
                              void* d_out, int out_size, void* d_ws, size_t ws_size,
                              hipStream_t stream) {
    const float* x    = (const float*)d_in[0];
    const float* Wih0 = (const float*)d_in[1];
    const float* Whh0 = (const float*)d_in[2];
    const float* bih0 = (const float*)d_in[3];
    const float* bhh0 = (const float*)d_in[4];
    const float* Wih1 = (const float*)d_in[5];
    const float* Whh1 = (const float*)d_in[6];
    const float* bih1 = (const float*)d_in[7];
    const float* bhh1 = (const float*)d_in[8];
    const float* ln_g = (const float*)d_in[9];
    const float* ln_b = (const float*)d_in[10];
    const float* fc1w = (const float*)d_in[11];
    const float* fc1b = (const float*)d_in[12];
    const float* fc2w = (const float*)d_in[13];
    const float* fc2b = (const float*)d_in[14];

    char* ws = (char*)d_ws;
    uint32*   h1k   = (uint32*)  (ws);                 // 64 blk x 256 t x 4 KiB = 64 MiB
    ushort_t* wf0   = (ushort_t*)(ws + 67108864);      // 192 KiB
    ushort_t* wf1   = (ushort_t*)(ws + 67305472);      // 256 KiB
    float*    bp0   = (float*)   (ws + 67567616);      // 2 KiB
    float*    bp1   = (float*)   (ws + 67569664);      // 2 KiB
    float*    lastH = (float*)   (ws + 67571712);      // 512 KiB
    uint32*   flags = (uint32*)  (ws + 68096000);      // 8 KiB (64 flags, 128 B apart)

    prep_frag<0><<<384, 256, 0, stream>>>(Whh0, Wih0, wf0);
    prep_frag<1><<<512, 256, 0, stream>>>(Whh1, Wih1, wf1);
    prep_bias<<<4, 256, 0, stream>>>(bih0, bhh0, bih1, bhh1, bp0, bp1, flags);

    lstm_pipe<<<128, 512, 0, stream>>>(x, wf0, wf1, bp0, bp1, h1k, lastH, flags);

    head_kernel<<<256, 256, 0, stream>>>(lastH, ln_g, ln_b, fc1w, fc1b, fc2w, fc2b,
                                         (float*)d_out);
}

// Round 9
// 364.430 us; speedup vs baseline: 1.3879x; 1.0595x over previous
//
#include <hip/hip_runtime.h>

typedef unsigned short ushort_t;
typedef unsigned int uint32;
typedef unsigned long long ull;
typedef __attribute__((ext_vector_type(8))) short short8;
typedef __attribute__((ext_vector_type(4))) float f32x4;

#define LOG2E   1.4426950408889634f
#define LOG2E2  2.8853900817779268f
#define MFMA16  __builtin_amdgcn_mfma_f32_16x16x32_bf16

static __device__ __forceinline__ ushort_t f2bf(float f) {
    uint32 u = __float_as_uint(f);
    u += 0x7FFFu + ((u >> 16) & 1u);
    return (ushort_t)(u >> 16);
}
static __device__ __forceinline__ float rcp_(float x) { return __builtin_amdgcn_rcpf(x); }
static __device__ __forceinline__ float ex2_(float x) { return __builtin_amdgcn_exp2f(x); }
// sigmoid with pre-scaled arg (x already multiplied by log2e)
static __device__ __forceinline__ float sigp_(float x) { return rcp_(1.0f + ex2_(-x)); }

// gates (i,f,g,o pre-scaled by log2e / 2log2e) -> new cell + h
static __device__ __forceinline__ float gate_update(const f32x4 a, float& cc) {
    float i_ = sigp_(a[0]);
    float f_ = sigp_(a[1]);
    float g_ = fmaf(2.f, sigp_(a[2]), -1.f);
    float o_ = sigp_(a[3]);
    cc = fmaf(f_, cc, i_ * g_);
    return o_ * fmaf(2.f, sigp_(cc * LOG2E2), -1.f);
}

// ---------------- prep: pack W into MFMA A-fragments (8-wave / 4-tile geometry) ----
// Wave w in [0,8), tile tq in [0,4). Tile row m = kga*4 + j (j = gate i,f,g,o)
// -> weight row = j*128 + hc, hc = w*16 + kga*4 + tq. Pre-scaled log2e / 2log2e(g).
template<int LAYER>
__global__ void prep_frag(const float* __restrict__ Whh, const float* __restrict__ Wih,
                          ushort_t* __restrict__ wfrag) {
    constexpr int KT  = (LAYER == 0) ? 6 : 8;
    constexpr int DIN = (LAYER == 0) ? 64 : 128;
    int i = blockIdx.x * 256 + threadIdx.x;
    int e    = i & 7;
    int lane = (i >> 3) & 63;
    int r3   = i >> 9;
    int kt   = r3 % KT;
    int r4   = r3 / KT;
    int tq   = r4 & 3;
    int w    = r4 >> 2;
    if (w >= 8) return;
    int ml  = lane & 15;
    int kga = ml >> 2;
    int j   = ml & 3;
    int k   = kt * 32 + (lane >> 4) * 8 + e;
    int row = j * 128 + w * 16 + kga * 4 + tq;
    float scale = (j == 2) ? LOG2E2 : LOG2E;
    float v = (k < 128) ? Whh[row * 128 + k] : Wih[row * DIN + (k - 128)];
    wfrag[i] = f2bf(v * scale);
}

__global__ void prep_bias(const float* __restrict__ bih0, const float* __restrict__ bhh0,
                          const float* __restrict__ bih1, const float* __restrict__ bhh1,
                          float* __restrict__ bp0, float* __restrict__ bp1,
                          uint32* __restrict__ flags) {
    int i = blockIdx.x * 256 + threadIdx.x;   // 0..1023
    flags[i] = 0u;                            // reset pipeline flags (graph-replay safe)
    flags[i + 1024] = 0u;
    int p = i & 511;
    int w = p >> 6, tq = (p >> 4) & 3, kga = (p >> 2) & 3, j = p & 3;
    int row = j * 128 + w * 16 + kga * 4 + tq;
    float scale = (j == 2) ? LOG2E2 : LOG2E;
    if (i < 512) bp0[p] = (bih0[row] + bhh0[row]) * scale;
    else         bp1[p] = (bih1[row] + bhh1[row]) * scale;
}

// ---------------- pipelined 2-layer LSTM, one dispatch ----------------
// 128 blocks x 512 threads (8 waves, 2/EU -> 256-reg budget). Blocks 0..63 = L0
// (producer), 64..127 = L1 (consumer), paired on batch group (b and b+64 land on
// the same XCD under round-robin). Producer stores k-major h-records one step
// late as single 8-B agent atomics; flag = producer step count, published every
// 4 steps (records <= flag-1 guaranteed visible). Consumer needs a lead of only
// ~3 steps. x-decoupling: xacc[t+1] MFMAs are recurrence-independent and are
// interleaved with the gate VALU so both pipes stay fed.
template<int KT, bool IS_L0>
__device__ __forceinline__ void run_phase(
    const int blk,
    const float* __restrict__ xin_f32,     // IS_L0: [B,T,64] f32
    const uint32* __restrict__ xin_rec,    // !IS_L0: k-major records
    const ushort_t* __restrict__ wfrag,
    const float* __restrict__ biasp,
    uint32* __restrict__ hrec,             // IS_L0 out
    float* __restrict__ lastH,             // !IS_L0 out
    uint32* __restrict__ flagp,
    ushort_t* hb, ushort_t* xb)
{
    constexpr int KX = KT - 4;
    constexpr int XW = KX * 256;           // u32 per x slot
    const int tid  = threadIdx.x;
    const int w    = tid >> 6;
    const int lane = tid & 63;
    const int n    = lane & 15;
    const int kg   = lane >> 4;
    const int b0   = blk * 16;

    // weights -> registers (held entire phase), split h-part / x-part
    short8 wfh[4][4];
    short8 wfx[4][KX];
#pragma unroll
    for (int tq = 0; tq < 4; ++tq) {
#pragma unroll
        for (int kt = 0; kt < 4; ++kt)
            wfh[tq][kt] = *(const short8*)&wfrag[(((w * 4 + tq) * KT + kt) * 64 + lane) * 8];
#pragma unroll
        for (int kx = 0; kx < KX; ++kx)
            wfx[tq][kx] = *(const short8*)&wfrag[(((w * 4 + tq) * KT + 4 + kx) * 64 + lane) * 8];
    }
    f32x4 bias[4];
#pragma unroll
    for (int tq = 0; tq < 4; ++tq)
        bias[tq] = *(const f32x4*)&biasp[w * 64 + tq * 16 + kg * 4];

    float cc[4] = {0.f, 0.f, 0.f, 0.f};
    const int f0   = w * 16 + kg * 4;
    const int idxA = ((f0 >> 5) * 4 + ((f0 >> 3) & 3)) * 64 + n * 4 + ((f0 & 7) >> 1);
    const int foff = kg * 128 + n * 8;

    // staging maps
    const int se  = (tid & 3) * 2;
    const int sn  = (tid >> 2) & 15;
    const int skg = (tid >> 6) & 3;
    const int skx = tid >> 8;
    const long xbase = (long)(b0 + sn) * (256 * 64) + (skx * 32 + skg * 8 + se);
    const int  sidx  = (skx * 4 + skg) * 64 + sn * 4 + (se >> 1);
    const long rb    = (long)blk * (256 * 1024);     // u32 units

    // incremental record pointers (no per-step 64-bit address math)
    ull* stp = (ull*)&hrec[rb + idxA];                           // producer: record 0
    const ull* ldp = (const ull*)&xin_rec[rb + 2048 + 2 * tid];  // consumer: record 2

    uint32 lastF = 0;

    // prologue: zero h state (slot 0), stage x[0]->slot0, x[1]->slot1
    ((uint32*)hb)[tid] = 0u;
    ((uint32*)hb)[tid + 512] = 0u;
    if constexpr (IS_L0) {
        float2 x0 = *(const float2*)&xin_f32[xbase];
        float2 x1 = *(const float2*)&xin_f32[xbase + 64];
        uint32 p0, p1;
        asm("v_cvt_pk_bf16_f32 %0, %1, %2" : "=v"(p0) : "v"(x0.x), "v"(x0.y));
        asm("v_cvt_pk_bf16_f32 %0, %1, %2" : "=v"(p1) : "v"(x1.x), "v"(x1.y));
        ((uint32*)xb)[sidx] = p0;
        ((uint32*)xb)[XW + sidx] = p1;
    } else {
        lastF = __hip_atomic_load(flagp, __ATOMIC_ACQUIRE, __HIP_MEMORY_SCOPE_AGENT);
        while (lastF < 3u) {      // records 0,1 visible
            __builtin_amdgcn_s_sleep(4);
            lastF = __hip_atomic_load(flagp, __ATOMIC_ACQUIRE, __HIP_MEMORY_SCOPE_AGENT);
        }
        ull r0 = __hip_atomic_load((const ull*)&xin_rec[rb + 2 * tid],        __ATOMIC_RELAXED, __HIP_MEMORY_SCOPE_AGENT);
        ull r1 = __hip_atomic_load((const ull*)&xin_rec[rb + 1024 + 2 * tid], __ATOMIC_RELAXED, __HIP_MEMORY_SCOPE_AGENT);
        *(ull*)&((uint32*)xb)[2 * tid]      = r0;
        *(ull*)&((uint32*)xb)[XW + 2 * tid] = r1;
    }
    __syncthreads();

    // xacc for step 0 from x[0] (slot 0)
    f32x4 xacc[4];
    {
        short8 xf_[KX];
#pragma unroll
        for (int kx = 0; kx < KX; ++kx)
            xf_[kx] = *(const short8*)&xb[kx * 512 + foff];
#pragma unroll
        for (int tq = 0; tq < 4; ++tq) {
            xacc[tq] = MFMA16(wfx[tq][0], xf_[0], bias[tq], 0, 0, 0);
#pragma unroll
            for (int kx = 1; kx < KX; ++kx)
                xacc[tq] = MFMA16(wfx[tq][kx], xf_[kx], xacc[tq], 0, 0, 0);
        }
    }
    __syncthreads();   // protect slot 0 before step-0 overwrites it with x[2]

    uint2 prev = {0u, 0u};
#pragma unroll 1
    for (int t = 0; t < 255; ++t) {
        const int cs = t & 1;
        const bool pf2 = (t < 254);                  // x[t+2] exists
        float2 xf = {0.f, 0.f}; ull xu64 = 0;
        if (pf2) {
            if constexpr (IS_L0) {
                xf = *(const float2*)&xin_f32[xbase + (long)(t + 2) * 64];
            } else {
                const uint32 want = (uint32)(t + 3);     // need record t+2
                if (lastF < want) {
                    lastF = __hip_atomic_load(flagp, __ATOMIC_ACQUIRE, __HIP_MEMORY_SCOPE_AGENT);
                    while (lastF < want) {
                        __builtin_amdgcn_s_sleep(4);
                        lastF = __hip_atomic_load(flagp, __ATOMIC_ACQUIRE, __HIP_MEMORY_SCOPE_AGENT);
                    }
                }
                xu64 = __hip_atomic_load(ldp, __ATOMIC_RELAXED, __HIP_MEMORY_SCOPE_AGENT);
                ldp += 512;
            }
        }
        // store previous step's record (full step of slack before the next drain)
        if constexpr (IS_L0) {
            if (t > 0) {
                __hip_atomic_store(stp, __builtin_bit_cast(ull, prev),
                                   __ATOMIC_RELAXED, __HIP_MEMORY_SCOPE_AGENT);
                stp += 512;
            }
        }

        // fragments
        short8 hfr[4];
#pragma unroll
        for (int kt = 0; kt < 4; ++kt)
            hfr[kt] = *(const short8*)&hb[cs * 2048 + kt * 512 + foff];
        short8 xfr[KX];
#pragma unroll
        for (int kx = 0; kx < KX; ++kx)
            xfr[kx] = *(const short8*)&xb[(cs ^ 1) * (KX * 512) + kx * 512 + foff];

        // gates for step t: 4-deep h-chains, C-in = xacc (bias + x[t] part)
        f32x4 acc[4];
#pragma unroll
        for (int tq = 0; tq < 4; ++tq) {
            acc[tq] = MFMA16(wfh[tq][0], hfr[0], xacc[tq], 0, 0, 0);
#pragma unroll
            for (int kt = 1; kt < 4; ++kt)
                acc[tq] = MFMA16(wfh[tq][kt], hfr[kt], acc[tq], 0, 0, 0);
        }
        // xacc(t+1) tiles 0,1 — independent MFMAs...
#pragma unroll
        for (int tq = 0; tq < 2; ++tq) {
            xacc[tq] = MFMA16(wfx[tq][0], xfr[0], bias[tq], 0, 0, 0);
#pragma unroll
            for (int kx = 1; kx < KX; ++kx)
                xacc[tq] = MFMA16(wfx[tq][kx], xfr[kx], xacc[tq], 0, 0, 0);
        }
        // ...gate VALU for tiles 0,1 issues under them
        float hv0 = gate_update(acc[0], cc[0]);
        float hv1 = gate_update(acc[1], cc[1]);
        // xacc(t+1) tiles 2,3
#pragma unroll
        for (int tq = 2; tq < 4; ++tq) {
            xacc[tq] = MFMA16(wfx[tq][0], xfr[0], bias[tq], 0, 0, 0);
#pragma unroll
            for (int kx = 1; kx < KX; ++kx)
                xacc[tq] = MFMA16(wfx[tq][kx], xfr[kx], xacc[tq], 0, 0, 0);
        }
        float hv2 = gate_update(acc[2], cc[2]);
        float hv3 = gate_update(acc[3], cc[3]);

        uint32 hp0, hp1;
        asm("v_cvt_pk_bf16_f32 %0, %1, %2" : "=v"(hp0) : "v"(hv0), "v"(hv1));
        asm("v_cvt_pk_bf16_f32 %0, %1, %2" : "=v"(hp1) : "v"(hv2), "v"(hv3));
        prev.x = hp0; prev.y = hp1;
        *(uint2*)&((uint32*)hb)[(cs ^ 1) * 1024 + idxA] = prev;

        if (pf2) {
            if constexpr (IS_L0) {
                uint32 xp;
                asm("v_cvt_pk_bf16_f32 %0, %1, %2" : "=v"(xp) : "v"(xf.x), "v"(xf.y));
                ((uint32*)xb)[cs * XW + sidx] = xp;
            } else {
                *(ull*)&((uint32*)xb)[cs * XW + 2 * tid] = xu64;
            }
        }
        __syncthreads();
        if constexpr (IS_L0) {
            // flag = t: records <= t-1 stored and drained by the barrier above
            if (tid == 0 && t != 0 && (t & 3) == 0)
                __hip_atomic_store(flagp, (uint32)t, __ATOMIC_RELEASE, __HIP_MEMORY_SCOPE_AGENT);
        }
    }

    // t = 255 (peeled): gates only; h state in slot 1
    {
        short8 hfr[4];
#pragma unroll
        for (int kt = 0; kt < 4; ++kt)
            hfr[kt] = *(const short8*)&hb[2048 + kt * 512 + foff];
        f32x4 acc[4];
#pragma unroll
        for (int tq = 0; tq < 4; ++tq) {
            acc[tq] = MFMA16(wfh[tq][0], hfr[0], xacc[tq], 0, 0, 0);
#pragma unroll
            for (int kt = 1; kt < 4; ++kt)
                acc[tq] = MFMA16(wfh[tq][kt], hfr[kt], acc[tq], 0, 0, 0);
        }
        float hv0 = gate_update(acc[0], cc[0]);
        float hv1 = gate_update(acc[1], cc[1]);
        float hv2 = gate_update(acc[2], cc[2]);
        float hv3 = gate_update(acc[3], cc[3]);
        if constexpr (IS_L0) {
            uint32 hp0, hp1;
            asm("v_cvt_pk_bf16_f32 %0, %1, %2" : "=v"(hp0) : "v"(hv0), "v"(hv1));
            asm("v_cvt_pk_bf16_f32 %0, %1, %2" : "=v"(hp1) : "v"(hv2), "v"(hv3));
            uint2 last; last.x = hp0; last.y = hp1;
            __hip_atomic_store(stp, __builtin_bit_cast(ull, prev),
                               __ATOMIC_RELAXED, __HIP_MEMORY_SCOPE_AGENT);   // record 254
            __hip_atomic_store(stp + 512, __builtin_bit_cast(ull, last),
                               __ATOMIC_RELAXED, __HIP_MEMORY_SCOPE_AGENT);   // record 255
            __syncthreads();   // drains all waves' stores (vmcnt(0) before barrier)
            if (tid == 0)
                __hip_atomic_store(flagp, 256u, __ATOMIC_RELEASE, __HIP_MEMORY_SCOPE_AGENT);
        } else {
            f32x4 hv = {hv0, hv1, hv2, hv3};
            *(f32x4*)&lastH[(long)(b0 + n) * 128 + f0] = hv;
        }
    }
}

__global__ __launch_bounds__(512, 2)
void lstm_pipe(const float* __restrict__ x,
               const ushort_t* __restrict__ wf0, const ushort_t* __restrict__ wf1,
               const float* __restrict__ bp0, const float* __restrict__ bp1,
               uint32* __restrict__ h1k, float* __restrict__ lastH,
               uint32* __restrict__ flags)
{
    __shared__ ushort_t hb[4096];   // 8 KiB: h double buffer
    __shared__ ushort_t xb[4096];   // 8 KiB: x double buffer (L0 uses half)
    const int blk = blockIdx.x;
    if (blk < 64)
        run_phase<6, true >(blk, x, nullptr, wf0, bp0, h1k, nullptr,
                            &flags[blk * 32], hb, xb);
    else
        run_phase<8, false>(blk - 64, nullptr, h1k, wf1, bp1, nullptr, lastH,
                            &flags[(blk - 64) * 32], hb, xb);
}

// ---------------- head: LayerNorm + fc1(relu) + fc2 ----------------
__global__ __launch_bounds__(256)
void head_kernel(const float* __restrict__ lastH,
                 const float* __restrict__ ln_g, const float* __restrict__ ln_b,
                 const float* __restrict__ fc1w, const float* __restrict__ fc1b,
                 const float* __restrict__ fc2w, const float* __restrict__ fc2b,
                 float* __restrict__ out) {
    __shared__ float ylds[4][128];
    int w = threadIdx.x >> 6, lane = threadIdx.x & 63;
    int row = blockIdx.x * 4 + w;
    float x0 = lastH[row * 128 + lane];
    float x1 = lastH[row * 128 + 64 + lane];
    float s = x0 + x1;
    for (int off = 32; off; off >>= 1) s += __shfl_xor(s, off);
    float mu = s * (1.f / 128.f);
    float d0 = x0 - mu, d1 = x1 - mu;
    float v = d0 * d0 + d1 * d1;
    for (int off = 32; off; off >>= 1) v += __shfl_xor(v, off);
    float rs = rsqrtf(v * (1.f / 128.f) + 1e-5f);
    ylds[w][lane]      = d0 * rs * ln_g[lane]      + ln_b[lane];
    ylds[w][lane + 64] = d1 * rs * ln_g[lane + 64] + ln_b[lane + 64];
    __syncthreads();
    float a = fc1b[lane];
#pragma unroll 4
    for (int k = 0; k < 128; ++k) a += ylds[w][k] * fc1w[lane * 128 + k];
    float r = fmaxf(a, 0.f) * fc2w[lane];
    for (int off = 32; off; off >>= 1) r += __shfl_xor(r, off);
    if (lane == 0) out[row] = r + fc2b[0];
}

extern "C" void kernel_launch(void* const* d_in, const int* in_sizes, int n_in,
                              void* d_out, int out_size, void* d_ws, size_t ws_size,
                              hipStream_t stream) {
    const float* x    = (const float*)d_in[0];
    const float* Wih0 = (const float*)d_in[1];
    const float* Whh0 = (const float*)d_in[2];
    const float* bih0 = (const float*)d_in[3];
    const float* bhh0 = (const float*)d_in[4];
    const float* Wih1 = (const float*)d_in[5];
    const float* Whh1 = (const float*)d_in[6];
    const float* bih1 = (const float*)d_in[7];
    const float* bhh1 = (const float*)d_in[8];
    const float* ln_g = (const float*)d_in[9];
    const float* ln_b = (const float*)d_in[10];
    const float* fc1w = (const float*)d_in[11];
    const float* fc1b = (const float*)d_in[12];
    const float* fc2w = (const float*)d_in[13];
    const float* fc2b = (const float*)d_in[14];

    char* ws = (char*)d_ws;
    uint32*   h1k   = (uint32*)  (ws);                 // 64 blk x 256 t x 4 KiB = 64 MiB
    ushort_t* wf0   = (ushort_t*)(ws + 67108864);      // 192 KiB
    ushort_t* wf1   = (ushort_t*)(ws + 67305472);      // 256 KiB
    float*    bp0   = (float*)   (ws + 67567616);      // 2 KiB
    float*    bp1   = (float*)   (ws + 67569664);      // 2 KiB
    float*    lastH = (float*)   (ws + 67571712);      // 512 KiB
    uint32*   flags = (uint32*)  (ws + 68096000);      // 8 KiB (64 flags, 128 B apart)

    prep_frag<0><<<384, 256, 0, stream>>>(Whh0, Wih0, wf0);
    prep_frag<1><<<512, 256, 0, stream>>>(Whh1, Wih1, wf1);
    prep_bias<<<4, 256, 0, stream>>>(bih0, bhh0, bih1, bhh1, bp0, bp1, flags);

    lstm_pipe<<<128, 512, 0, stream>>>(x, wf0, wf1, bp0, bp1, h1k, lastH, flags);

    head_kernel<<<256, 256, 0, stream>>>(lastH, ln_g, ln_b, fc1w, fc1b, fc2w, fc2b,
                                         (float*)d_out);
}

// Round 10
// 339.071 us; speedup vs baseline: 1.4917x; 1.0748x over previous
//
#include <hip/hip_runtime.h>

typedef unsigned short ushort_t;
typedef unsigned int uint32;
typedef unsigned long long ull;
typedef __attribute__((ext_vector_type(8))) short short8;
typedef __attribute__((ext_vector_type(4))) float f32x4;
typedef __attribute__((ext_vector_type(2))) unsigned long long ull2;

#define LOG2E   1.4426950408889634f
#define LOG2E2  2.8853900817779268f
#define MFMA16  __builtin_amdgcn_mfma_f32_16x16x32_bf16

static __device__ __forceinline__ ushort_t f2bf(float f) {
    uint32 u = __float_as_uint(f);
    u += 0x7FFFu + ((u >> 16) & 1u);
    return (ushort_t)(u >> 16);
}
static __device__ __forceinline__ float rcp_(float x) { return __builtin_amdgcn_rcpf(x); }
static __device__ __forceinline__ float ex2_(float x) { return __builtin_amdgcn_exp2f(x); }
// sigmoid with pre-scaled arg (x already multiplied by log2e)
static __device__ __forceinline__ float sigp_(float x) { return rcp_(1.0f + ex2_(-x)); }

static __device__ __forceinline__ float gate_update(const f32x4 a, float& cc) {
    float i_ = sigp_(a[0]);
    float f_ = sigp_(a[1]);
    float g_ = fmaf(2.f, sigp_(a[2]), -1.f);
    float o_ = sigp_(a[3]);
    cc = fmaf(f_, cc, i_ * g_);
    return o_ * fmaf(2.f, sigp_(cc * LOG2E2), -1.f);
}
static __device__ __forceinline__ uint2 pack4(float a, float b, float c, float d) {
    uint2 r;
    asm("v_cvt_pk_bf16_f32 %0, %1, %2" : "=v"(r.x) : "v"(a), "v"(b));
    asm("v_cvt_pk_bf16_f32 %0, %1, %2" : "=v"(r.y) : "v"(c), "v"(d));
    return r;
}

// ---------------- prep (unchanged from round 9) ----------------
template<int LAYER>
__global__ void prep_frag(const float* __restrict__ Whh, const float* __restrict__ Wih,
                          ushort_t* __restrict__ wfrag) {
    constexpr int KT  = (LAYER == 0) ? 6 : 8;
    constexpr int DIN = (LAYER == 0) ? 64 : 128;
    int i = blockIdx.x * 256 + threadIdx.x;
    int e    = i & 7;
    int lane = (i >> 3) & 63;
    int r3   = i >> 9;
    int kt   = r3 % KT;
    int r4   = r3 / KT;
    int tq   = r4 & 3;
    int w    = r4 >> 2;
    if (w >= 8) return;
    int ml  = lane & 15;
    int kga = ml >> 2;
    int j   = ml & 3;
    int k   = kt * 32 + (lane >> 4) * 8 + e;
    int row = j * 128 + w * 16 + kga * 4 + tq;
    float scale = (j == 2) ? LOG2E2 : LOG2E;
    float v = (k < 128) ? Whh[row * 128 + k] : Wih[row * DIN + (k - 128)];
    wfrag[i] = f2bf(v * scale);
}

__global__ void prep_bias(const float* __restrict__ bih0, const float* __restrict__ bhh0,
                          const float* __restrict__ bih1, const float* __restrict__ bhh1,
                          float* __restrict__ bp0, float* __restrict__ bp1,
                          uint32* __restrict__ flags) {
    int i = blockIdx.x * 256 + threadIdx.x;   // 0..1023
    flags[i] = 0u;                            // reset pipeline flags (graph-replay safe)
    flags[i + 1024] = 0u;
    int p = i & 511;
    int w = p >> 6, tq = (p >> 4) & 3, kga = (p >> 2) & 3, j = p & 3;
    int row = j * 128 + w * 16 + kga * 4 + tq;
    float scale = (j == 2) ? LOG2E2 : LOG2E;
    if (i < 512) bp0[p] = (bih0[row] + bhh0[row]) * scale;
    else         bp1[p] = (bih1[row] + bhh1[row]) * scale;
}

// ---------------- M-role: h-chain MFMA + elementwise (critical path only) ------
// Waves 0..3. Wave w owns h-cols [w*32, w*32+32) = prep tiles w8 in {2w, 2w+1},
// tq 0..3. C-in = xacc quads from accq[P] (written by V-waves in step t-1).
// Gates stay in registers; h written to hb[P^1]; no global/flag/staging work.
template<int KT, bool IS_L0>
__device__ __forceinline__ void m_loop(const int blk, const ushort_t* __restrict__ wfrag,
                                       float* __restrict__ lastH,
                                       ushort_t* hb, float* accq)
{
    const int tid  = threadIdx.x;
    const int w    = tid >> 6;            // 0..3
    const int lane = tid & 63;
    const int n    = lane & 15;
    const int kg   = lane >> 4;
    const int foff = kg * 128 + n * 8;
    const int b0   = blk * 16;

    short8 wfh[2][4][4];
#pragma unroll
    for (int s = 0; s < 2; ++s)
#pragma unroll
        for (int tq = 0; tq < 4; ++tq)
#pragma unroll
            for (int kt = 0; kt < 4; ++kt)
                wfh[s][tq][kt] = *(const short8*)
                    &wfrag[((((2 * w + s) * 4 + tq) * KT + kt) * 64 + lane) * 8];

    float cc0[4] = {0, 0, 0, 0}, cc1[4] = {0, 0, 0, 0};
    const int hc0 = (2 * w) * 16 + kg * 4;
    const int hc1 = (2 * w + 1) * 16 + kg * 4;
    const int qa0 = hc0 * 64 + n * 4;     // float idx of first C-in quad
    const int qa1 = hc1 * 64 + n * 4;
    const int hw0 = ((hc0 >> 5) * 4 + ((hc0 >> 3) & 3)) * 128 + n * 8 + (hc0 & 7);
    const int hw1 = ((hc1 >> 5) * 4 + ((hc1 >> 3) & 3)) * 128 + n * 8 + (hc1 & 7);

    __syncthreads();   // V staged xb0/xb1
    __syncthreads();   // V wrote xacc[0] -> accq[0]

#define MSTEP(P, T)                                                                \
    {                                                                              \
        f32x4 a0[4], a1[4];                                                        \
        _Pragma("unroll")                                                          \
        for (int tq = 0; tq < 4; ++tq) {                                           \
            a0[tq] = *(const f32x4*)&accq[(P) * 8192 + qa0 + tq * 64];             \
            a1[tq] = *(const f32x4*)&accq[(P) * 8192 + qa1 + tq * 64];             \
        }                                                                          \
        short8 hfr[4];                                                             \
        _Pragma("unroll")                                                          \
        for (int kt = 0; kt < 4; ++kt)                                             \
            hfr[kt] = *(const short8*)&hb[(P) * 2048 + kt * 512 + foff];           \
        _Pragma("unroll")                                                          \
        for (int kt = 0; kt < 4; ++kt) {                                           \
            _Pragma("unroll")                                                      \
            for (int tq = 0; tq < 4; ++tq) {                                       \
                a0[tq] = MFMA16(wfh[0][tq][kt], hfr[kt], a0[tq], 0, 0, 0);         \
                a1[tq] = MFMA16(wfh[1][tq][kt], hfr[kt], a1[tq], 0, 0, 0);         \
            }                                                                      \
        }                                                                          \
        float hv00 = gate_update(a0[0], cc0[0]);                                   \
        float hv01 = gate_update(a0[1], cc0[1]);                                   \
        float hv02 = gate_update(a0[2], cc0[2]);                                   \
        float hv03 = gate_update(a0[3], cc0[3]);                                   \
        float hv10 = gate_update(a1[0], cc1[0]);                                   \
        float hv11 = gate_update(a1[1], cc1[1]);                                   \
        float hv12 = gate_update(a1[2], cc1[2]);                                   \
        float hv13 = gate_update(a1[3], cc1[3]);                                   \
        uint2 q0 = pack4(hv00, hv01, hv02, hv03);                                  \
        uint2 q1 = pack4(hv10, hv11, hv12, hv13);                                  \
        *(uint2*)&hb[((P) ^ 1) * 2048 + hw0] = q0;                                 \
        *(uint2*)&hb[((P) ^ 1) * 2048 + hw1] = q1;                                 \
        if (!IS_L0 && (T) == 255) {                                                \
            f32x4 o0 = {hv00, hv01, hv02, hv03};                                   \
            f32x4 o1 = {hv10, hv11, hv12, hv13};                                   \
            *(f32x4*)&lastH[(long)(b0 + n) * 128 + hc0] = o0;                      \
            *(f32x4*)&lastH[(long)(b0 + n) * 128 + hc1] = o1;                      \
        }                                                                          \
        __syncthreads();                                                           \
    }

#pragma unroll 1
    for (int t = 0; t < 256; t += 2) {
        MSTEP(0, t)
        MSTEP(1, t + 1)
    }
#undef MSTEP
}

// ---------------- V-role: xacc MFMA + all staging / record IO / flags ----------
// Waves 4..7 (v = w-4). Computes xacc[t+1] = bias + Wx*x[t+1] into accq[(t+1)&1];
// stages x/records 3 deep; producer stores h-records (one step late) and flags.
template<int KT, bool IS_L0>
__device__ __forceinline__ void v_loop(const int blk,
    const float* __restrict__ xin_f32, const uint32* __restrict__ xin_rec,
    const ushort_t* __restrict__ wfrag, const float* __restrict__ biasp,
    uint32* __restrict__ hrec, uint32* __restrict__ flagp,
    ushort_t* hb, ushort_t* xb, float* accq)
{
    constexpr int KX  = KT - 4;
    constexpr int XBS = KX * 512;         // ushorts per xb slot
    const int tid  = threadIdx.x;
    const int v    = (tid >> 6) - 4;      // 0..3
    const int lane = tid & 63;
    const int n    = lane & 15;
    const int kg   = lane >> 4;
    const int foff = kg * 128 + n * 8;
    const int vtid = tid - 256;           // 0..255
    const int b0   = blk * 16;

    short8 wfx[2][4][KX];
#pragma unroll
    for (int s = 0; s < 2; ++s)
#pragma unroll
        for (int tq = 0; tq < 4; ++tq)
#pragma unroll
            for (int kx = 0; kx < KX; ++kx)
                wfx[s][tq][kx] = *(const short8*)
                    &wfrag[((((2 * v + s) * 4 + tq) * KT + 4 + kx) * 64 + lane) * 8];
    f32x4 bias[2][4];
#pragma unroll
    for (int s = 0; s < 2; ++s)
#pragma unroll
        for (int tq = 0; tq < 4; ++tq)
            bias[s][tq] = *(const f32x4*)&biasp[(2 * v + s) * 64 + tq * 16 + kg * 4];

    const int hc0 = (2 * v) * 16 + kg * 4;
    const int hc1 = (2 * v + 1) * 16 + kg * 4;
    const int qa0 = hc0 * 64 + n * 4;
    const int qa1 = hc1 * 64 + n * 4;

    // staging maps
    const int skx = vtid >> 7;                       // L0: 0..1
    const int skg = (vtid >> 5) & 3;
    const int sn  = (vtid >> 1) & 15;
    const int se4 = (vtid & 1) * 4;
    const long xgbase = (long)(b0 + sn) * (256 * 64) + skx * 32 + skg * 8 + se4;
    const int  sxoff  = (skx * 4 + skg) * 128 + sn * 8 + se4;   // ushort idx
    const long rb     = (long)blk * (256 * 1024);               // u32 units
    ull*       stp    = (ull*)&hrec[rb] + vtid * 2;             // record 0
    const ull* ldp    = (const ull*)&xin_rec[rb + 3 * 1024] + vtid * 2;  // record 3
    uint32 lastF = 0;
    uint2  xpack = {0u, 0u};
    ull    r64a = 0, r64b = 0;

    // prologue: stage x/rec[0]->xb0, [1]->xb1, [2]->regs
    if (IS_L0) {
        f32x4 x0 = *(const f32x4*)&xin_f32[xgbase];
        f32x4 x1 = *(const f32x4*)&xin_f32[xgbase + 64];
        f32x4 x2 = *(const f32x4*)&xin_f32[xgbase + 128];
        *(uint2*)&xb[0 * XBS + sxoff] = pack4(x0[0], x0[1], x0[2], x0[3]);
        *(uint2*)&xb[1 * XBS + sxoff] = pack4(x1[0], x1[1], x1[2], x1[3]);
        xpack = pack4(x2[0], x2[1], x2[2], x2[3]);
    } else {
        lastF = __hip_atomic_load(flagp, __ATOMIC_ACQUIRE, __HIP_MEMORY_SCOPE_AGENT);
        while (lastF < 4u) {
            __builtin_amdgcn_s_sleep(4);
            lastF = __hip_atomic_load(flagp, __ATOMIC_ACQUIRE, __HIP_MEMORY_SCOPE_AGENT);
        }
        const ull* p0 = (const ull*)&xin_rec[rb] + vtid * 2;
        ull a0_ = __hip_atomic_load(p0,            __ATOMIC_RELAXED, __HIP_MEMORY_SCOPE_AGENT);
        ull a1_ = __hip_atomic_load(p0 + 1,        __ATOMIC_RELAXED, __HIP_MEMORY_SCOPE_AGENT);
        ull b0_ = __hip_atomic_load(p0 + 512,      __ATOMIC_RELAXED, __HIP_MEMORY_SCOPE_AGENT);
        ull b1_ = __hip_atomic_load(p0 + 513,      __ATOMIC_RELAXED, __HIP_MEMORY_SCOPE_AGENT);
        r64a    = __hip_atomic_load(p0 + 1024,     __ATOMIC_RELAXED, __HIP_MEMORY_SCOPE_AGENT);
        r64b    = __hip_atomic_load(p0 + 1025,     __ATOMIC_RELAXED, __HIP_MEMORY_SCOPE_AGENT);
        ull2 w0; w0[0] = a0_; w0[1] = a1_;
        ull2 w1; w1[0] = b0_; w1[1] = b1_;
        *(ull2*)&xb[0 * XBS + vtid * 8] = w0;
        *(ull2*)&xb[1 * XBS + vtid * 8] = w1;
    }
    __syncthreads();   // xb0/xb1 visible

    // xacc[0] -> accq[0]
    {
        short8 xfr[KX];
#pragma unroll
        for (int kx = 0; kx < KX; ++kx)
            xfr[kx] = *(const short8*)&xb[0 * XBS + kx * 512 + foff];
#pragma unroll
        for (int tq = 0; tq < 4; ++tq) {
            f32x4 xa0 = bias[0][tq], xa1 = bias[1][tq];
#pragma unroll
            for (int kx = 0; kx < KX; ++kx) {
                xa0 = MFMA16(wfx[0][tq][kx], xfr[kx], xa0, 0, 0, 0);
                xa1 = MFMA16(wfx[1][tq][kx], xfr[kx], xa1, 0, 0, 0);
            }
            *(f32x4*)&accq[qa0 + tq * 64] = xa0;
            *(f32x4*)&accq[qa1 + tq * 64] = xa1;
        }
    }
    __syncthreads();   // accq[0] visible

#define VSTEP(P, T)                                                                \
    {                                                                              \
        if ((T) < 255) {                                                           \
            short8 xfr[KX];                                                        \
            _Pragma("unroll")                                                      \
            for (int kx = 0; kx < KX; ++kx)                                        \
                xfr[kx] = *(const short8*)&xb[((P) ^ 1) * XBS + kx * 512 + foff];  \
            _Pragma("unroll")                                                      \
            for (int tq = 0; tq < 4; ++tq) {                                       \
                f32x4 xa0 = bias[0][tq], xa1 = bias[1][tq];                        \
                _Pragma("unroll")                                                  \
                for (int kx = 0; kx < KX; ++kx) {                                  \
                    xa0 = MFMA16(wfx[0][tq][kx], xfr[kx], xa0, 0, 0, 0);           \
                    xa1 = MFMA16(wfx[1][tq][kx], xfr[kx], xa1, 0, 0, 0);           \
                }                                                                  \
                *(f32x4*)&accq[((P) ^ 1) * 8192 + qa0 + tq * 64] = xa0;            \
                *(f32x4*)&accq[((P) ^ 1) * 8192 + qa1 + tq * 64] = xa1;            \
            }                                                                      \
        }                                                                          \
        if ((T) + 2 < 256) {                                                       \
            if (IS_L0) {                                                           \
                *(uint2*)&xb[(P) * XBS + sxoff] = xpack;                           \
            } else {                                                               \
                ull2 wv; wv[0] = r64a; wv[1] = r64b;                               \
                *(ull2*)&xb[(P) * XBS + vtid * 8] = wv;                            \
            }                                                                      \
        }                                                                          \
        if ((T) + 3 < 256) {                                                       \
            if (IS_L0) {                                                           \
                f32x4 xv = *(const f32x4*)&xin_f32[xgbase + (long)((T) + 3) * 64]; \
                xpack = pack4(xv[0], xv[1], xv[2], xv[3]);                         \
            } else {                                                               \
                const uint32 want = (uint32)((T) + 4);                             \
                if (lastF < want) {                                                \
                    lastF = __hip_atomic_load(flagp, __ATOMIC_ACQUIRE, __HIP_MEMORY_SCOPE_AGENT); \
                    while (lastF < want) {                                         \
                        __builtin_amdgcn_s_sleep(4);                               \
                        lastF = __hip_atomic_load(flagp, __ATOMIC_ACQUIRE, __HIP_MEMORY_SCOPE_AGENT); \
                    }                                                              \
                }                                                                  \
                r64a = __hip_atomic_load(ldp,     __ATOMIC_RELAXED, __HIP_MEMORY_SCOPE_AGENT); \
                r64b = __hip_atomic_load(ldp + 1, __ATOMIC_RELAXED, __HIP_MEMORY_SCOPE_AGENT); \
                ldp += 512;                                                        \
            }                                                                      \
        }                                                                          \
        if (IS_L0 && (T) >= 1) {                                                   \
            ull2 rr = __builtin_bit_cast(ull2,                                     \
                          *(const short8*)&hb[(P) * 2048 + vtid * 8]);             \
            __hip_atomic_store(stp,     rr[0], __ATOMIC_RELAXED, __HIP_MEMORY_SCOPE_AGENT); \
            __hip_atomic_store(stp + 1, rr[1], __ATOMIC_RELAXED, __HIP_MEMORY_SCOPE_AGENT); \
            stp += 512;                                                            \
        }                                                                          \
        __syncthreads();                                                           \
        if (IS_L0 && vtid == 0 && ((T) & 1) == 0 && (T) >= 2)                      \
            __hip_atomic_store(flagp, (uint32)(T), __ATOMIC_RELEASE, __HIP_MEMORY_SCOPE_AGENT); \
    }

#pragma unroll 1
    for (int t = 0; t < 256; t += 2) {
        VSTEP(0, t)
        VSTEP(1, t + 1)
    }
#undef VSTEP

    // record 255 (h[255] sits in hb parity 0)
    if (IS_L0) {
        ull2 rr = __builtin_bit_cast(ull2, *(const short8*)&hb[vtid * 8]);
        __hip_atomic_store(stp,     rr[0], __ATOMIC_RELAXED, __HIP_MEMORY_SCOPE_AGENT);
        __hip_atomic_store(stp + 1, rr[1], __ATOMIC_RELAXED, __HIP_MEMORY_SCOPE_AGENT);
    }
}

__global__ __launch_bounds__(512, 2)
void lstm_pipe(const float* __restrict__ x,
               const ushort_t* __restrict__ wf0, const ushort_t* __restrict__ wf1,
               const float* __restrict__ bp0, const float* __restrict__ bp1,
               uint32* __restrict__ h1k, float* __restrict__ lastH,
               uint32* __restrict__ flags)
{
    __shared__ ushort_t hb[4096];        // 8 KiB: h double buffer
    __shared__ ushort_t xb[4096];        // 8 KiB: x double buffer
    __shared__ float    accq[16384];     // 64 KiB: xacc quad double buffer
    const int blk = blockIdx.x;
    const int tid = threadIdx.x;
    ((uint32*)hb)[tid]       = 0u;       // zero h state (parity 0)
    ((uint32*)hb)[tid + 512] = 0u;
    if (blk < 64) {
        if (tid < 256) m_loop<6, true >(blk, wf0, nullptr, hb, accq);
        else           v_loop<6, true >(blk, x, nullptr, wf0, bp0, h1k,
                                        &flags[blk * 32], hb, xb, accq);
    } else {
        const int b = blk - 64;
        if (tid < 256) m_loop<8, false>(b, wf1, lastH, hb, accq);
        else           v_loop<8, false>(b, nullptr, h1k, wf1, bp1, nullptr,
                                        &flags[b * 32], hb, xb, accq);
    }
    __syncthreads();   // drain all waves' final stores
    if (blk < 64 && tid == 256)
        __hip_atomic_store(&flags[blk * 32], 1000u, __ATOMIC_RELEASE, __HIP_MEMORY_SCOPE_AGENT);
}

// ---------------- head: LayerNorm + fc1(relu) + fc2 ----------------
__global__ __launch_bounds__(256)
void head_kernel(const float* __restrict__ lastH,
                 const float* __restrict__ ln_g, const float* __restrict__ ln_b,
                 const float* __restrict__ fc1w, const float* __restrict__ fc1b,
                 const float* __restrict__ fc2w, const float* __restrict__ fc2b,
                 float* __restrict__ out) {
    __shared__ float ylds[4][128];
    int w = threadIdx.x >> 6, lane = threadIdx.x & 63;
    int row = blockIdx.x * 4 + w;
    float x0 = lastH[row * 128 + lane];
    float x1 = lastH[row * 128 + 64 + lane];
    float s = x0 + x1;
    for (int off = 32; off; off >>= 1) s += __shfl_xor(s, off);
    float mu = s * (1.f / 128.f);
    float d0 = x0 - mu, d1 = x1 - mu;
    float v = d0 * d0 + d1 * d1;
    for (int off = 32; off; off >>= 1) v += __shfl_xor(v, off);
    float rs = rsqrtf(v * (1.f / 128.f) + 1e-5f);
    ylds[w][lane]      = d0 * rs * ln_g[lane]      + ln_b[lane];
    ylds[w][lane + 64] = d1 * rs * ln_g[lane + 64] + ln_b[lane + 64];
    __syncthreads();
    float a = fc1b[lane];
#pragma unroll 4
    for (int k = 0; k < 128; ++k) a += ylds[w][k] * fc1w[lane * 128 + k];
    float r = fmaxf(a, 0.f) * fc2w[lane];
    for (int off = 32; off; off >>= 1) r += __shfl_xor(r, off);
    if (lane == 0) out[row] = r + fc2b[0];
}

extern "C" void kernel_launch(void* const* d_in, const int* in_sizes, int n_in,
                              void* d_out, int out_size, void* d_ws, size_t ws_size,
                              hipStream_t stream) {
    const float* x    = (const float*)d_in[0];
    const float* Wih0 = (const float*)d_in[1];
    const float* Whh0 = (const float*)d_in[2];
    const float* bih0 = (const float*)d_in[3];
    const float* bhh0 = (const float*)d_in[4];
    const float* Wih1 = (const float*)d_in[5];
    const float* Whh1 = (const float*)d_in[6];
    const float* bih1 = (const float*)d_in[7];
    const float* bhh1 = (const float*)d_in[8];
    const float* ln_g = (const float*)d_in[9];
    const float* ln_b = (const float*)d_in[10];
    const float* fc1w = (const float*)d_in[11];
    const float* fc1b = (const float*)d_in[12];
    const float* fc2w = (const float*)d_in[13];
    const float* fc2b = (const float*)d_in[14];

    char* ws = (char*)d_ws;
    uint32*   h1k   = (uint32*)  (ws);                 // 64 blk x 256 t x 4 KiB = 64 MiB
    ushort_t* wf0   = (ushort_t*)(ws + 67108864);      // 192 KiB
    ushort_t* wf1   = (ushort_t*)(ws + 67305472);      // 256 KiB
    float*    bp0   = (float*)   (ws + 67567616);      // 2 KiB
    float*    bp1   = (float*)   (ws + 67569664);      // 2 KiB
    float*    lastH = (float*)   (ws + 67571712);      // 512 KiB
    uint32*   flags = (uint32*)  (ws + 68096000);      // 8 KiB (64 flags, 128 B apart)

    prep_frag<0><<<384, 256, 0, stream>>>(Whh0, Wih0, wf0);
    prep_frag<1><<<512, 256, 0, stream>>>(Whh1, Wih1, wf1);
    prep_bias<<<4, 256, 0, stream>>>(bih0, bhh0, bih1, bhh1, bp0, bp1, flags);

    lstm_pipe<<<128, 512, 0, stream>>>(x, wf0, wf1, bp0, bp1, h1k, lastH, flags);

    head_kernel<<<256, 256, 0, stream>>>(lastH, ln_g, ln_b, fc1w, fc1b, fc2w, fc2b,
                                         (float*)d_out);
}